// Round 1
// 328.739 us; speedup vs baseline: 1.0337x; 1.0337x over previous
//
#include <hip/hip_runtime.h>

#define T_SEQ 512
#define INPUT 14
#define HID 8
#define TC 16
#define NCHUNK (T_SEQ / TC)
#define BN_EPS 1e-5f

typedef float v2f __attribute__((ext_vector_type(2)));

__device__ __forceinline__ float fast_exp2(float x) { return __builtin_amdgcn_exp2f(x); }
__device__ __forceinline__ float fast_rcp(float x)  { return __builtin_amdgcn_rcpf(x); }

// packed fp32 math (CDNA2+): one instruction, two FMAs per lane
__device__ __forceinline__ v2f pk_fma(v2f a, v2f b, v2f c) {
    v2f d;
    asm("v_pk_fma_f32 %0, %1, %2, %3" : "=v"(d) : "v"(a), "v"(b), "v"(c));
    return d;
}
__device__ __forceinline__ v2f pk_mul(v2f a, v2f b) {
    v2f d;
    asm("v_pk_mul_f32 %0, %1, %2" : "=v"(d) : "v"(a), "v"(b));
    return d;
}

// ds_swizzle (LDS crossbar): BitMode imm = xor<<10 | or<<5 | and
template <int IMM>
__device__ __forceinline__ float swz(float v) {
    return __int_as_float(__builtin_amdgcn_ds_swizzle(__float_as_int(v), IMM));
}

// DPP cross-lane ops (VALU pipe)
#define DPP_BC0  0x00   // quad_perm [0,0,0,0] : broadcast quad-lane 0 (gate i)
#define DPP_BC1  0x55   // quad_perm [1,1,1,1] : broadcast quad-lane 1 (gate f)
#define DPP_BC2  0xAA   // quad_perm [2,2,2,2] : broadcast quad-lane 2 (gate g)
#define DPP_BC3  0xFF   // quad_perm [3,3,3,3] : broadcast quad-lane 3 (gate o)
#define DPP_XOR8 0x128  // row_ror:8 : lane ^= 8 within 16-row
template <int CTRL>
__device__ __forceinline__ float dpp(float v) {
    return __int_as_float(__builtin_amdgcn_update_dpp(
        0, __float_as_int(v), CTRL, 0xF, 0xF, true));
}

// UNIT-MAJOR layout: lane(within 32) = unit*4 + type.
// Butterfly images of h over unit bits (lane bits 2..4): hx[m] = h at lane^(4m).
__device__ __forceinline__ void butterfly8u(float h, float (&hx)[8]) {
    hx[0] = h;
    float x4  = swz<0x101F>(h);    // xor 4
    float x16 = swz<0x401F>(h);    // xor 16
    float x20 = swz<0x501F>(h);    // xor 20
    hx[1] = x4;
    hx[2] = dpp<DPP_XOR8>(h);      // xor 8
    hx[3] = dpp<DPP_XOR8>(x4);     // xor 12
    hx[4] = x16;
    hx[5] = x20;
    hx[6] = dpp<DPP_XOR8>(x16);    // xor 24
    hx[7] = dpp<DPP_XOR8>(x20);    // xor 28
}

// Block: 256 threads = 4 waves; each wave handles 2 batch elements (32 lanes each).
// Within 32 lanes: unit = (l5>>2)&7, type = l5&3 (0=i,1=f,2=g,3=o -- PyTorch order),
// weight row = type*8 + unit.
// Numeric scheme: all gate-row weights/biases are pre-scaled by the lane's exp2
// activation constant (-1.4427 for sigmoid lanes, -2.885 for the tanh lane), so
// exp2(acc) needs no pre-multiply. The cell state is kept PRE-SCALED (C = -2.885*c):
// the g-lane emits -2.885*tanh(g) (folded into actMul/actAdd), so C = F*C + P'
// feeds tanh(c) = 2*rcp(1+exp2(C)) - 1 with no scale mul on the chain.
__global__ __launch_bounds__(256, 2)
void lstm_forex_kernel(const float* __restrict__ x,
                       const float* __restrict__ Wih1, const float* __restrict__ Whh1,
                       const float* __restrict__ bih1, const float* __restrict__ bhh1,
                       const float* __restrict__ Wih2, const float* __restrict__ Whh2,
                       const float* __restrict__ bih2, const float* __restrict__ bhh2,
                       const float* __restrict__ bn_gamma, const float* __restrict__ bn_beta,
                       const float* __restrict__ bn_mean, const float* __restrict__ bn_var,
                       const float* __restrict__ w1p, const float* __restrict__ b1p,
                       const float* __restrict__ w2p, const float* __restrict__ b2p,
                       float* __restrict__ out)
{
    __shared__ float xbuf[4][2][TC][16];   // [wave][elem][t][14 padded to 16]

    const int tid  = threadIdx.x;
    const int wave = tid >> 6;
    const int lane = tid & 63;
    const int grp  = lane >> 5;          // which of the wave's 2 batch elements
    const int l5   = lane & 31;
    const int u    = (l5 >> 2) & 7;      // unit
    const int type = l5 & 3;             // gate type
    const int row  = type * 8 + u;       // weight row (PyTorch i,f,g,o blocks)

    const int b = blockIdx.x * 8 + wave * 2 + grp;

    // exp2-domain activation constants; scale folded into weights below
    const float gateScale = (type == 2) ? -2.885390082f : -1.4426950408f;
    const float actMul    = (type == 2) ? -5.770780164f : 1.f;   // g-lane outputs -2.885*tanh(g)
    const float actAdd    = (type == 2) ?  2.885390082f : 0.f;

    // ---- per-lane weight rows (pre-scaled); recurrent mats pre-permuted for XOR butterfly ----
    v2f   wi1p[7];
    float wh1p[8], wi2p[8], wh2p[8];
#pragma unroll
    for (int k = 0; k < 7; ++k) {
        wi1p[k] = (v2f){ Wih1[row * INPUT + 2 * k]     * gateScale,
                         Wih1[row * INPUT + 2 * k + 1] * gateScale };
    }
#pragma unroll
    for (int m = 0; m < 8; ++m) {
        int j = u ^ m;
        wh1p[m] = Whh1[row * HID + j] * gateScale;
        wi2p[m] = Wih2[row * HID + j] * gateScale;
        wh2p[m] = Whh2[row * HID + j] * gateScale;
    }
    const float bsum1s = (bih1[row] + bhh1[row]) * gateScale;
    const float bsum2s = (bih2[row] + bhh2[row]) * gateScale;
    const v2f   bias1  = { bsum1s, 0.f };

    // ---- x staging: 448 dwords per wave-chunk (2 elems * 16 t * 14), 7 per lane ----
    const float* gptr[7];
    int loff[7];
#pragma unroll
    for (int it = 0; it < 7; ++it) {
        int d   = it * 64 + lane;       // coalesced flat dword index within wave-chunk
        int es  = d / 224;              // which elem
        int idx = d - es * 224;         // dword within elem's 16x14 chunk
        int tr  = idx / 14;
        int k   = idx - tr * 14;
        int bb  = blockIdx.x * 8 + wave * 2 + es;
        gptr[it] = x + (size_t)bb * (T_SEQ * INPUT) + idx;
        loff[it] = es * (TC * 16) + tr * 16 + k;   // padded LDS layout
    }

    float hx1[8], hx2[8];               // butterfly images of h1, h2
    float c1 = 0.f, c2 = 0.f;           // PRE-SCALED cell states (C = -2.885*c)
#pragma unroll
    for (int m = 0; m < 8; ++m) { hx1[m] = 0.f; hx2[m] = 0.f; }

    // prefetch chunk 0
    float st[7];
#pragma unroll
    for (int it = 0; it < 7; ++it) { st[it] = *gptr[it]; gptr[it] += TC * INPUT; }

    float (*xw)[TC][16] = xbuf[wave];

    for (int c = 0; c < NCHUNK; ++c) {
        // stage chunk c into LDS (in-order DS per wave makes this visible to reads below)
#pragma unroll
        for (int it = 0; it < 7; ++it) ((float*)xw)[loff[it]] = st[it];
        // prefetch chunk c+1 while computing chunk c
        if (c + 1 < NCHUNK) {
#pragma unroll
            for (int it = 0; it < 7; ++it) { st[it] = *gptr[it]; gptr[it] += TC * INPUT; }
        }
        __builtin_amdgcn_wave_barrier();

#pragma unroll
        for (int t = 0; t < TC; ++t) {
            const float* xrow = &xw[grp][t][0];
            float4 xa = *(const float4*)(xrow + 0);
            float4 xb = *(const float4*)(xrow + 4);
            float4 xc = *(const float4*)(xrow + 8);
            float2 xd = *(const float2*)(xrow + 12);

            // ---- layer 1 x-projection: 7 packed FMAs (off critical path; its issue
            //      slack also hides the butterfly swizzle latency from last step) ----
            v2f ax0 = pk_fma((v2f){xa.x, xa.y}, wi1p[0], bias1);
            v2f ax1 = pk_mul((v2f){xa.z, xa.w}, wi1p[1]);
            ax0 = pk_fma((v2f){xb.x, xb.y}, wi1p[2], ax0);
            ax1 = pk_fma((v2f){xb.z, xb.w}, wi1p[3], ax1);
            ax0 = pk_fma((v2f){xc.x, xc.y}, wi1p[4], ax0);
            ax1 = pk_fma((v2f){xc.z, xc.w}, wi1p[5], ax1);
            ax0 = pk_fma((v2f){xd.x, xd.y}, wi1p[6], ax0);

            // layer-2 recurrent part (uses h2 of previous step -- off chain)
            float q0 = fmaf(hx2[0], wh2p[0], bsum2s);
            float q1 = hx2[1] * wh2p[1];
            float q2 = hx2[2] * wh2p[2];
            float q3 = hx2[3] * wh2p[3];
            q0 = fmaf(hx2[4], wh2p[4], q0);
            q1 = fmaf(hx2[5], wh2p[5], q1);
            q2 = fmaf(hx2[6], wh2p[6], q2);
            q3 = fmaf(hx2[7], wh2p[7], q3);

            // layer-1 recurrent butterfly dot: 4 chains of 2, depth 4 from hx1
            float a0 = fmaf(hx1[0], wh1p[0], ax0.x);
            float a1 = fmaf(hx1[1], wh1p[1], ax0.y);
            float a2 = fmaf(hx1[2], wh1p[2], ax1.x);
            float a3 = fmaf(hx1[3], wh1p[3], ax1.y);
            a0 = fmaf(hx1[4], wh1p[4], a0);
            a1 = fmaf(hx1[5], wh1p[5], a1);
            a2 = fmaf(hx1[6], wh1p[6], a2);
            a3 = fmaf(hx1[7], wh1p[7], a3);
            float acc = (a0 + a1) + (a2 + a3);

            // own-gate activation (weights pre-scaled: no mul before exp2)
            float v0 = fmaf(fast_rcp(1.f + fast_exp2(acc)), actMul, actAdd);
            // quad broadcasts: every lane receives (i, f, g', o) directly
            float vi = dpp<DPP_BC0>(v0);
            float vf = dpp<DPP_BC1>(v0);
            float vg = dpp<DPP_BC2>(v0);   // = -2.885*tanh(g)
            float vo = dpp<DPP_BC3>(v0);
            c1 = fmaf(vf, c1, vi * vg);    // scaled cell update
            float th1 = fmaf(fast_rcp(1.f + fast_exp2(c1)), 2.f, -1.f);
            float h1u = vo * th1;          // every lane holds h1[own unit]
            butterfly8u(h1u, hx1);         // 3 swz + 4 dpp

            // ---- layer 2 ----
            float p0 = fmaf(hx1[0], wi2p[0], q0);
            float p1 = fmaf(hx1[1], wi2p[1], q1);
            float p2 = fmaf(hx1[2], wi2p[2], q2);
            float p3 = fmaf(hx1[3], wi2p[3], q3);
            p0 = fmaf(hx1[4], wi2p[4], p0);
            p1 = fmaf(hx1[5], wi2p[5], p1);
            p2 = fmaf(hx1[6], wi2p[6], p2);
            p3 = fmaf(hx1[7], wi2p[7], p3);
            float acc2 = (p0 + p1) + (p2 + p3);

            float u0 = fmaf(fast_rcp(1.f + fast_exp2(acc2)), actMul, actAdd);
            float ui = dpp<DPP_BC0>(u0);
            float uf = dpp<DPP_BC1>(u0);
            float ug = dpp<DPP_BC2>(u0);
            float uo = dpp<DPP_BC3>(u0);
            c2 = fmaf(uf, c2, ui * ug);
            float th2 = fmaf(fast_rcp(1.f + fast_exp2(c2)), 2.f, -1.f);
            float h2u = uo * th2;
            butterfly8u(h2u, hx2);
        }
    }

    // ---- BN (eval) + MLP head, one lane per batch element ----
    // At l5==0 (u==0, type==0): hx2[m] = h2 at lane 4m = h2[m].
    if (l5 == 0) {
        float nd[HID];
#pragma unroll
        for (int j = 0; j < HID; ++j) {
            float inv = 1.f / sqrtf(bn_var[j] + BN_EPS);
            nd[j] = bn_gamma[j] * (hx2[j] - bn_mean[j]) * inv + bn_beta[j];
        }
        float acc = b2p[0];
#pragma unroll
        for (int m = 0; m < 4; ++m) {
            float s = b1p[m];
#pragma unroll
            for (int j = 0; j < HID; ++j) s = fmaf(nd[j], w1p[m * HID + j], s);
            s = fmaxf(s, 0.f);
            acc = fmaf(s, w2p[m], acc);
        }
        out[b] = acc;
    }
}

extern "C" void kernel_launch(void* const* d_in, const int* in_sizes, int n_in,
                              void* d_out, int out_size, void* d_ws, size_t ws_size,
                              hipStream_t stream) {
    const float* x        = (const float*)d_in[0];
    const float* Wih1     = (const float*)d_in[1];
    const float* Whh1     = (const float*)d_in[2];
    const float* bih1     = (const float*)d_in[3];
    const float* bhh1     = (const float*)d_in[4];
    const float* Wih2     = (const float*)d_in[5];
    const float* Whh2     = (const float*)d_in[6];
    const float* bih2     = (const float*)d_in[7];
    const float* bhh2     = (const float*)d_in[8];
    const float* bn_gamma = (const float*)d_in[9];
    const float* bn_beta  = (const float*)d_in[10];
    const float* bn_mean  = (const float*)d_in[11];
    const float* bn_var   = (const float*)d_in[12];
    const float* w1p      = (const float*)d_in[13];
    const float* b1p      = (const float*)d_in[14];
    const float* w2p      = (const float*)d_in[15];
    const float* b2p      = (const float*)d_in[16];
    float* out = (float*)d_out;

    const int B = in_sizes[0] / (T_SEQ * INPUT);   // 4096
    dim3 grid(B / 8), block(256);
    hipLaunchKernelGGL(lstm_forex_kernel, grid, block, 0, stream,
                       x, Wih1, Whh1, bih1, bhh1, Wih2, Whh2, bih2, bhh2,
                       bn_gamma, bn_beta, bn_mean, bn_var, w1p, b1p, w2p, b2p, out);
}

// Round 2
// 318.720 us; speedup vs baseline: 1.0662x; 1.0314x over previous
//
#include <hip/hip_runtime.h>

#define T_SEQ 512
#define INPUT 14
#define HID 8
#define TC 16
#define NCHUNK (T_SEQ / TC)
#define BN_EPS 1e-5f

typedef float v2f __attribute__((ext_vector_type(2)));

__device__ __forceinline__ float fast_exp2(float x) { return __builtin_amdgcn_exp2f(x); }
__device__ __forceinline__ float fast_rcp(float x)  { return __builtin_amdgcn_rcpf(x); }

// packed fp32 math (CDNA): one instruction, two FMAs per lane
__device__ __forceinline__ v2f pk_fma(v2f a, v2f b, v2f c) {
    v2f d;
    asm("v_pk_fma_f32 %0, %1, %2, %3" : "=v"(d) : "v"(a), "v"(b), "v"(c));
    return d;
}
__device__ __forceinline__ v2f pk_mul(v2f a, v2f b) {
    v2f d;
    asm("v_pk_mul_f32 %0, %1, %2" : "=v"(d) : "v"(a), "v"(b));
    return d;
}
__device__ __forceinline__ v2f pk_add(v2f a, v2f b) {
    v2f d;
    asm("v_pk_add_f32 %0, %1, %2" : "=v"(d) : "v"(a), "v"(b));
    return d;
}

// ds_swizzle (LDS crossbar): BitMode imm = xor<<10 | or<<5 | and
template <int IMM>
__device__ __forceinline__ float swz(float v) {
    return __int_as_float(__builtin_amdgcn_ds_swizzle(__float_as_int(v), IMM));
}

// DPP cross-lane ops (VALU pipe)
#define DPP_BC0  0x00   // quad_perm [0,0,0,0] : broadcast quad-lane 0 (gate i)
#define DPP_BC1  0x55   // quad_perm [1,1,1,1] : broadcast quad-lane 1 (gate f)
#define DPP_BC2  0xAA   // quad_perm [2,2,2,2] : broadcast quad-lane 2 (gate g)
#define DPP_BC3  0xFF   // quad_perm [3,3,3,3] : broadcast quad-lane 3 (gate o)
#define DPP_XOR8 0x128  // row_ror:8 : lane ^= 8 within 16-row
template <int CTRL>
__device__ __forceinline__ float dpp(float v) {
    return __int_as_float(__builtin_amdgcn_update_dpp(
        0, __float_as_int(v), CTRL, 0xF, 0xF, true));
}

// UNIT-MAJOR layout: lane(within 32) = unit*4 + type.
// Butterfly images of h over unit bits (lane bits 2..4), stored as v2f PAIRS so the
// recurrent dots can use v_pk_fma_f32: hx[p] = {img(2p), img(2p+1)}, img m = h at lane^(4m).
__device__ __forceinline__ void butterfly8v(float h, v2f (&hx)[4]) {
    float x4  = swz<0x101F>(h);    // xor 4
    float x16 = swz<0x401F>(h);    // xor 16
    float x20 = swz<0x501F>(h);    // xor 20
    hx[0].x = h;
    hx[0].y = x4;
    hx[1].x = dpp<DPP_XOR8>(h);    // xor 8
    hx[1].y = dpp<DPP_XOR8>(x4);   // xor 12
    hx[2].x = x16;
    hx[2].y = x20;
    hx[3].x = dpp<DPP_XOR8>(x16);  // xor 24
    hx[3].y = dpp<DPP_XOR8>(x20);  // xor 28
}

// Block: 256 threads = 4 waves; each wave handles 2 batch elements (32 lanes each).
// Within 32 lanes: unit = (l5>>2)&7, type = l5&3 (0=i,1=f,2=g,3=o -- PyTorch order),
// weight row = type*8 + unit.
// Numeric scheme: all gate-row weights/biases pre-scaled by the lane's exp2 activation
// constant; cell state kept PRE-SCALED (C = -2.885*c) so tanh(c) = 2*rcp(1+exp2(C))-1
// with no scale mul on the chain.
__global__ __launch_bounds__(256, 2)
void lstm_forex_kernel(const float* __restrict__ x,
                       const float* __restrict__ Wih1, const float* __restrict__ Whh1,
                       const float* __restrict__ bih1, const float* __restrict__ bhh1,
                       const float* __restrict__ Wih2, const float* __restrict__ Whh2,
                       const float* __restrict__ bih2, const float* __restrict__ bhh2,
                       const float* __restrict__ bn_gamma, const float* __restrict__ bn_beta,
                       const float* __restrict__ bn_mean, const float* __restrict__ bn_var,
                       const float* __restrict__ w1p, const float* __restrict__ b1p,
                       const float* __restrict__ w2p, const float* __restrict__ b2p,
                       float* __restrict__ out)
{
    __shared__ float xbuf[4][2][TC][16];   // [wave][elem][t][14 padded to 16]

    const int tid  = threadIdx.x;
    const int wave = tid >> 6;
    const int lane = tid & 63;
    const int grp  = lane >> 5;          // which of the wave's 2 batch elements
    const int l5   = lane & 31;
    const int u    = (l5 >> 2) & 7;      // unit
    const int type = l5 & 3;             // gate type
    const int row  = type * 8 + u;       // weight row (PyTorch i,f,g,o blocks)

    const int b = blockIdx.x * 8 + wave * 2 + grp;

    // exp2-domain activation constants; scale folded into weights below
    const float gateScale = (type == 2) ? -2.885390082f : -1.4426950408f;
    const float actMul    = (type == 2) ? -5.770780164f : 1.f;   // g-lane outputs -2.885*tanh(g)
    const float actAdd    = (type == 2) ?  2.885390082f : 0.f;

    // ---- per-lane weight rows (pre-scaled); recurrent mats pre-permuted for XOR
    //      butterfly and PAIRED to match the v2f image pairs ----
    v2f wi1p[7], wh1v[4], wi2v[4], wh2v[4];
#pragma unroll
    for (int k = 0; k < 7; ++k) {
        wi1p[k].x = Wih1[row * INPUT + 2 * k]     * gateScale;
        wi1p[k].y = Wih1[row * INPUT + 2 * k + 1] * gateScale;
    }
#pragma unroll
    for (int p = 0; p < 4; ++p) {
        int j0 = u ^ (2 * p), j1 = u ^ (2 * p + 1);
        wh1v[p].x = Whh1[row * HID + j0] * gateScale;
        wh1v[p].y = Whh1[row * HID + j1] * gateScale;
        wi2v[p].x = Wih2[row * HID + j0] * gateScale;
        wi2v[p].y = Wih2[row * HID + j1] * gateScale;
        wh2v[p].x = Whh2[row * HID + j0] * gateScale;
        wh2v[p].y = Whh2[row * HID + j1] * gateScale;
    }
    const float bsum1s = (bih1[row] + bhh1[row]) * gateScale;
    const float bsum2s = (bih2[row] + bhh2[row]) * gateScale;
    const v2f   bias1  = { bsum1s, 0.f };
    const v2f   bias2  = { bsum2s, 0.f };

    // ---- x staging: 448 dwords per wave-chunk (2 elems * 16 t * 14), 7 per lane ----
    const float* gptr[7];
    int loff[7];
#pragma unroll
    for (int it = 0; it < 7; ++it) {
        int d   = it * 64 + lane;       // coalesced flat dword index within wave-chunk
        int es  = d / 224;              // which elem
        int idx = d - es * 224;         // dword within elem's 16x14 chunk
        int tr  = idx / 14;
        int k   = idx - tr * 14;
        int bb  = blockIdx.x * 8 + wave * 2 + es;
        gptr[it] = x + (size_t)bb * (T_SEQ * INPUT) + idx;
        loff[it] = es * (TC * 16) + tr * 16 + k;   // padded LDS layout
    }

    v2f hx1[4], hx2[4];                 // paired butterfly images of h1, h2
    float c1 = 0.f, c2 = 0.f;           // PRE-SCALED cell states (C = -2.885*c)
#pragma unroll
    for (int p = 0; p < 4; ++p) { hx1[p] = (v2f){0.f, 0.f}; hx2[p] = (v2f){0.f, 0.f}; }

    // prefetch chunk 0
    float st[7];
#pragma unroll
    for (int it = 0; it < 7; ++it) { st[it] = *gptr[it]; gptr[it] += TC * INPUT; }

    float (*xw)[TC][16] = xbuf[wave];

    for (int c = 0; c < NCHUNK; ++c) {
        // stage chunk c into LDS (in-order DS per wave makes this visible to reads below)
#pragma unroll
        for (int it = 0; it < 7; ++it) ((float*)xw)[loff[it]] = st[it];
        // prefetch chunk c+1 while computing chunk c
        if (c + 1 < NCHUNK) {
#pragma unroll
            for (int it = 0; it < 7; ++it) { st[it] = *gptr[it]; gptr[it] += TC * INPUT; }
        }
        __builtin_amdgcn_wave_barrier();

#pragma unroll
        for (int t = 0; t < TC; ++t) {
            const float* xrow = &xw[grp][t][0];
            float4 xa = *(const float4*)(xrow + 0);
            float4 xb = *(const float4*)(xrow + 4);
            float4 xc = *(const float4*)(xrow + 8);
            float2 xd = *(const float2*)(xrow + 12);

            // ---- layer 1 x-projection: 7 packed FMAs (off critical path; its issue
            //      slack also hides the butterfly swizzle latency from last step) ----
            v2f ax0 = pk_fma((v2f){xa.x, xa.y}, wi1p[0], bias1);
            v2f ax1 = pk_mul((v2f){xa.z, xa.w}, wi1p[1]);
            ax0 = pk_fma((v2f){xb.x, xb.y}, wi1p[2], ax0);
            ax1 = pk_fma((v2f){xb.z, xb.w}, wi1p[3], ax1);
            ax0 = pk_fma((v2f){xc.x, xc.y}, wi1p[4], ax0);
            ax1 = pk_fma((v2f){xc.z, xc.w}, wi1p[5], ax1);
            ax0 = pk_fma((v2f){xd.x, xd.y}, wi1p[6], ax0);

            // layer-2 recurrent part (uses h2 of previous step -- off chain), kept packed
            v2f qA = pk_fma(hx2[0], wh2v[0], bias2);
            v2f qB = pk_mul(hx2[1], wh2v[1]);
            qA = pk_fma(hx2[2], wh2v[2], qA);
            qB = pk_fma(hx2[3], wh2v[3], qB);

            // layer-1 recurrent butterfly dot: 4 pk_fma + pk_add + add
            v2f sA = pk_fma(hx1[0], wh1v[0], ax0);
            v2f sB = pk_fma(hx1[1], wh1v[1], ax1);
            sA = pk_fma(hx1[2], wh1v[2], sA);
            sB = pk_fma(hx1[3], wh1v[3], sB);
            v2f sC = pk_add(sA, sB);
            float acc = sC.x + sC.y;

            // own-gate activation (weights pre-scaled: no mul before exp2)
            float v0 = fmaf(fast_rcp(1.f + fast_exp2(acc)), actMul, actAdd);
            // quad broadcasts: every lane receives (i, f, g', o) directly
            float vi = dpp<DPP_BC0>(v0);
            float vf = dpp<DPP_BC1>(v0);
            float vg = dpp<DPP_BC2>(v0);   // = -2.885*tanh(g)
            float vo = dpp<DPP_BC3>(v0);
            c1 = fmaf(vf, c1, vi * vg);    // scaled cell update
            float th1 = fmaf(fast_rcp(1.f + fast_exp2(c1)), 2.f, -1.f);
            float h1u = vo * th1;          // every lane holds h1[own unit]
            butterfly8v(h1u, hx1);         // 3 swz + 4 dpp

            // ---- layer 2: 4 pk_fma + pk_add + add on top of packed q ----
            v2f pA = pk_fma(hx1[0], wi2v[0], qA);
            v2f pB = pk_fma(hx1[1], wi2v[1], qB);
            pA = pk_fma(hx1[2], wi2v[2], pA);
            pB = pk_fma(hx1[3], wi2v[3], pB);
            v2f pC = pk_add(pA, pB);
            float acc2 = pC.x + pC.y;

            float u0 = fmaf(fast_rcp(1.f + fast_exp2(acc2)), actMul, actAdd);
            float ui = dpp<DPP_BC0>(u0);
            float uf = dpp<DPP_BC1>(u0);
            float ug = dpp<DPP_BC2>(u0);
            float uo = dpp<DPP_BC3>(u0);
            c2 = fmaf(uf, c2, ui * ug);
            float th2 = fmaf(fast_rcp(1.f + fast_exp2(c2)), 2.f, -1.f);
            float h2u = uo * th2;
            butterfly8v(h2u, hx2);
        }
    }

    // ---- BN (eval) + MLP head, one lane per batch element ----
    // At l5==0 (u==0, type==0): img m = h2[m]; pairs give h2[j] = hx2[j>>1][j&1].
    if (l5 == 0) {
        float h2v[HID];
#pragma unroll
        for (int j = 0; j < HID; ++j) h2v[j] = (j & 1) ? hx2[j >> 1].y : hx2[j >> 1].x;
        float nd[HID];
#pragma unroll
        for (int j = 0; j < HID; ++j) {
            float inv = 1.f / sqrtf(bn_var[j] + BN_EPS);
            nd[j] = bn_gamma[j] * (h2v[j] - bn_mean[j]) * inv + bn_beta[j];
        }
        float acc = b2p[0];
#pragma unroll
        for (int m = 0; m < 4; ++m) {
            float s = b1p[m];
#pragma unroll
            for (int j = 0; j < HID; ++j) s = fmaf(nd[j], w1p[m * HID + j], s);
            s = fmaxf(s, 0.f);
            acc = fmaf(s, w2p[m], acc);
        }
        out[b] = acc;
    }
}

extern "C" void kernel_launch(void* const* d_in, const int* in_sizes, int n_in,
                              void* d_out, int out_size, void* d_ws, size_t ws_size,
                              hipStream_t stream) {
    const float* x        = (const float*)d_in[0];
    const float* Wih1     = (const float*)d_in[1];
    const float* Whh1     = (const float*)d_in[2];
    const float* bih1     = (const float*)d_in[3];
    const float* bhh1     = (const float*)d_in[4];
    const float* Wih2     = (const float*)d_in[5];
    const float* Whh2     = (const float*)d_in[6];
    const float* bih2     = (const float*)d_in[7];
    const float* bhh2     = (const float*)d_in[8];
    const float* bn_gamma = (const float*)d_in[9];
    const float* bn_beta  = (const float*)d_in[10];
    const float* bn_mean  = (const float*)d_in[11];
    const float* bn_var   = (const float*)d_in[12];
    const float* w1p      = (const float*)d_in[13];
    const float* b1p      = (const float*)d_in[14];
    const float* w2p      = (const float*)d_in[15];
    const float* b2p      = (const float*)d_in[16];
    float* out = (float*)d_out;

    const int B = in_sizes[0] / (T_SEQ * INPUT);   // 4096
    dim3 grid(B / 8), block(256);
    hipLaunchKernelGGL(lstm_forex_kernel, grid, block, 0, stream,
                       x, Wih1, Whh1, bih1, bhh1, Wih2, Whh2, bih2, bhh2,
                       bn_gamma, bn_beta, bn_mean, bn_var, w1p, b1p, w2p, b2p, out);
}

// Round 3
// 315.418 us; speedup vs baseline: 1.0773x; 1.0105x over previous
//
#include <hip/hip_runtime.h>

#define T_SEQ 512
#define INPUT 14
#define HID 8
#define TC 16
#define NCHUNK (T_SEQ / TC)
#define BN_EPS 1e-5f

typedef float v2f __attribute__((ext_vector_type(2)));

__device__ __forceinline__ float fast_exp2(float x) { return __builtin_amdgcn_exp2f(x); }
__device__ __forceinline__ float fast_rcp(float x)  { return __builtin_amdgcn_rcpf(x); }

// packed fp32 math (CDNA): one instruction, two FMAs per lane
__device__ __forceinline__ v2f pk_fma(v2f a, v2f b, v2f c) {
    v2f d;
    asm("v_pk_fma_f32 %0, %1, %2, %3" : "=v"(d) : "v"(a), "v"(b), "v"(c));
    return d;
}
__device__ __forceinline__ v2f pk_mul(v2f a, v2f b) {
    v2f d;
    asm("v_pk_mul_f32 %0, %1, %2" : "=v"(d) : "v"(a), "v"(b));
    return d;
}
__device__ __forceinline__ v2f pk_add(v2f a, v2f b) {
    v2f d;
    asm("v_pk_add_f32 %0, %1, %2" : "=v"(d) : "v"(a), "v"(b));
    return d;
}

// ds_swizzle (LDS crossbar): BitMode imm = xor<<10 | or<<5 | and
template <int IMM>
__device__ __forceinline__ float swz(float v) {
    return __int_as_float(__builtin_amdgcn_ds_swizzle(__float_as_int(v), IMM));
}

// DPP cross-lane ops (VALU pipe)
#define DPP_BC0  0x00   // quad_perm [0,0,0,0] : broadcast quad-lane 0 (gate i)
#define DPP_BC1  0x55   // quad_perm [1,1,1,1] : broadcast quad-lane 1 (gate f)
#define DPP_BC2  0xAA   // quad_perm [2,2,2,2] : broadcast quad-lane 2 (gate g)
#define DPP_BC3  0xFF   // quad_perm [3,3,3,3] : broadcast quad-lane 3 (gate o)
#define DPP_XOR8 0x128  // row_ror:8 : lane ^= 8 within 16-row
template <int CTRL>
__device__ __forceinline__ float dpp(float v) {
    return __int_as_float(__builtin_amdgcn_update_dpp(
        0, __float_as_int(v), CTRL, 0xF, 0xF, true));
}

// UNIT-MAJOR layout: lane(within 32) = unit*4 + type.
// Butterfly images of h over unit bits (lane bits 2..4), paired so pair 0 is DPP-ONLY
// (no LDS crossbar on the first FMA): hx[0]={h,x8}, hx[1]={x4,x12}, hx[2]={x16,x24},
// hx[3]={x20,x28}.  offset 4m <-> unit xor m, so pair units are u^{0,2},{1,3},{4,6},{5,7}.
__device__ __forceinline__ void butterfly8v(float h, v2f (&hx)[4]) {
    float x8  = dpp<DPP_XOR8>(h);  // xor 8  (VALU, fast)
    float x4  = swz<0x101F>(h);    // xor 4  (LDS crossbar)
    float x16 = swz<0x401F>(h);    // xor 16
    float x20 = swz<0x501F>(h);    // xor 20
    hx[0].x = h;   hx[0].y = x8;
    hx[1].x = x4;  hx[1].y = dpp<DPP_XOR8>(x4);   // xor 12
    hx[2].x = x16; hx[2].y = dpp<DPP_XOR8>(x16);  // xor 24
    hx[3].x = x20; hx[3].y = dpp<DPP_XOR8>(x20);  // xor 28
}

// Block: 256 threads = 4 waves; each wave handles 2 batch elements (32 lanes each).
// Within 32 lanes: unit = (l5>>2)&7, type = l5&3 (0=i,1=f,2=g,3=o -- PyTorch order),
// weight row = type*8 + unit.
// Numeric scheme: all gate-row weights/biases pre-scaled by the lane's exp2 activation
// constant; cell state kept PRE-SCALED (C = -2.885*c) so tanh(c) = 2*rcp(1+exp2(C))-1
// with no scale mul on the chain.
// Structure: per 16-step chunk, Phase A computes all input projections xp[t] into
// REGISTERS (batched LDS reads, throughput-bound); Phase B runs the serial recurrence
// with ZERO LDS reads -- only the butterfly swizzles touch the in-order DS queue, so
// the chain-critical swizzle never waits behind x-tile reads.
__global__ __launch_bounds__(256, 2)
void lstm_forex_kernel(const float* __restrict__ x,
                       const float* __restrict__ Wih1, const float* __restrict__ Whh1,
                       const float* __restrict__ bih1, const float* __restrict__ bhh1,
                       const float* __restrict__ Wih2, const float* __restrict__ Whh2,
                       const float* __restrict__ bih2, const float* __restrict__ bhh2,
                       const float* __restrict__ bn_gamma, const float* __restrict__ bn_beta,
                       const float* __restrict__ bn_mean, const float* __restrict__ bn_var,
                       const float* __restrict__ w1p, const float* __restrict__ b1p,
                       const float* __restrict__ w2p, const float* __restrict__ b2p,
                       float* __restrict__ out)
{
    __shared__ float xbuf[4][2][TC][16];   // [wave][elem][t][14 padded to 16]

    const int tid  = threadIdx.x;
    const int wave = tid >> 6;
    const int lane = tid & 63;
    const int grp  = lane >> 5;          // which of the wave's 2 batch elements
    const int l5   = lane & 31;
    const int u    = (l5 >> 2) & 7;      // unit
    const int type = l5 & 3;             // gate type
    const int row  = type * 8 + u;       // weight row (PyTorch i,f,g,o blocks)

    const int b = blockIdx.x * 8 + wave * 2 + grp;

    // exp2-domain activation constants; scale folded into weights below
    const float gateScale = (type == 2) ? -2.885390082f : -1.4426950408f;
    const float actMul    = (type == 2) ? -5.770780164f : 1.f;   // g-lane outputs -2.885*tanh(g)
    const float actAdd    = (type == 2) ?  2.885390082f : 0.f;

    // ---- per-lane weight rows (pre-scaled); recurrent mats pre-permuted for XOR
    //      butterfly, paired to match the image pairs {0,2},{1,3},{4,6},{5,7} ----
    v2f wi1p[7], wh1v[4], wi2v[4], wh2v[4];
#pragma unroll
    for (int k = 0; k < 7; ++k) {
        wi1p[k].x = Wih1[row * INPUT + 2 * k]     * gateScale;
        wi1p[k].y = Wih1[row * INPUT + 2 * k + 1] * gateScale;
    }
    const int poff[4] = {0, 1, 4, 5};
#pragma unroll
    for (int p = 0; p < 4; ++p) {
        int j0 = u ^ poff[p], j1 = j0 ^ 2;
        wh1v[p].x = Whh1[row * HID + j0] * gateScale;
        wh1v[p].y = Whh1[row * HID + j1] * gateScale;
        wi2v[p].x = Wih2[row * HID + j0] * gateScale;
        wi2v[p].y = Wih2[row * HID + j1] * gateScale;
        wh2v[p].x = Whh2[row * HID + j0] * gateScale;
        wh2v[p].y = Whh2[row * HID + j1] * gateScale;
    }
    const float bsum1s = (bih1[row] + bhh1[row]) * gateScale;
    const float bsum2s = (bih2[row] + bhh2[row]) * gateScale;
    const v2f   bias1  = { bsum1s, 0.f };
    const v2f   bias2  = { bsum2s, 0.f };

    // ---- x staging: 448 dwords per wave-chunk (2 elems * 16 t * 14), 7 per lane ----
    const float* gptr[7];
    int loff[7];
#pragma unroll
    for (int it = 0; it < 7; ++it) {
        int d   = it * 64 + lane;       // coalesced flat dword index within wave-chunk
        int es  = d / 224;              // which elem
        int idx = d - es * 224;         // dword within elem's 16x14 chunk
        int tr  = idx / 14;
        int k   = idx - tr * 14;
        int bb  = blockIdx.x * 8 + wave * 2 + es;
        gptr[it] = x + (size_t)bb * (T_SEQ * INPUT) + idx;
        loff[it] = es * (TC * 16) + tr * 16 + k;   // padded LDS layout
    }

    v2f hx1[4], hx2[4];                 // paired butterfly images of h1, h2
    float c1 = 0.f, c2 = 0.f;           // PRE-SCALED cell states (C = -2.885*c)
#pragma unroll
    for (int p = 0; p < 4; ++p) { hx1[p] = (v2f){0.f, 0.f}; hx2[p] = (v2f){0.f, 0.f}; }

    // prefetch chunk 0
    float st[7];
#pragma unroll
    for (int it = 0; it < 7; ++it) { st[it] = *gptr[it]; gptr[it] += TC * INPUT; }

    float (*xw)[TC][16] = xbuf[wave];

    for (int c = 0; c < NCHUNK; ++c) {
        // stage chunk c into LDS (in-order DS per wave makes this visible to reads below)
#pragma unroll
        for (int it = 0; it < 7; ++it) ((float*)xw)[loff[it]] = st[it];
        // prefetch chunk c+1 while computing chunk c
        if (c + 1 < NCHUNK) {
#pragma unroll
            for (int it = 0; it < 7; ++it) { st[it] = *gptr[it]; gptr[it] += TC * INPUT; }
        }
        __builtin_amdgcn_wave_barrier();

        // ===== Phase A: batched x-projections for all 16 steps -> registers =====
        v2f xp0[TC], xp1[TC];
#pragma unroll
        for (int t = 0; t < TC; ++t) {
            const float* xrow = &xw[grp][t][0];
            float4 xa = *(const float4*)(xrow + 0);
            float4 xb = *(const float4*)(xrow + 4);
            float4 xc = *(const float4*)(xrow + 8);
            float2 xd = *(const float2*)(xrow + 12);
            v2f a0 = pk_fma((v2f){xa.x, xa.y}, wi1p[0], bias1);
            v2f a1 = pk_mul((v2f){xa.z, xa.w}, wi1p[1]);
            a0 = pk_fma((v2f){xb.x, xb.y}, wi1p[2], a0);
            a1 = pk_fma((v2f){xb.z, xb.w}, wi1p[3], a1);
            a0 = pk_fma((v2f){xc.x, xc.y}, wi1p[4], a0);
            a1 = pk_fma((v2f){xc.z, xc.w}, wi1p[5], a1);
            a0 = pk_fma((v2f){xd.x, xd.y}, wi1p[6], a0);
            xp0[t] = a0;
            xp1[t] = a1;
        }

        // ===== Phase B: serial recurrence, no LDS reads -- swizzles own the DS queue =====
#pragma unroll
        for (int t = 0; t < TC; ++t) {
            // layer-2 recurrent part (uses h2 of previous step -- off chain), kept packed
            v2f qA = pk_fma(hx2[0], wh2v[0], bias2);
            v2f qB = pk_mul(hx2[1], wh2v[1]);
            qA = pk_fma(hx2[2], wh2v[2], qA);
            qB = pk_fma(hx2[3], wh2v[3], qB);

            // layer-1 recurrent butterfly dot: pair 0 (DPP-only) first, swz pairs later
            v2f sA = pk_fma(hx1[0], wh1v[0], xp0[t]);
            v2f sB = pk_fma(hx1[1], wh1v[1], xp1[t]);
            sA = pk_fma(hx1[2], wh1v[2], sA);
            sB = pk_fma(hx1[3], wh1v[3], sB);
            v2f sC = pk_add(sA, sB);
            float acc = sC.x + sC.y;

            // own-gate activation (weights pre-scaled: no mul before exp2)
            float v0 = fmaf(fast_rcp(1.f + fast_exp2(acc)), actMul, actAdd);
            // quad broadcasts: every lane receives (i, f, g', o) directly
            float vi = dpp<DPP_BC0>(v0);
            float vf = dpp<DPP_BC1>(v0);
            float vg = dpp<DPP_BC2>(v0);   // = -2.885*tanh(g)
            float vo = dpp<DPP_BC3>(v0);
            c1 = fmaf(vf, c1, vi * vg);    // scaled cell update
            float th1 = fmaf(fast_rcp(1.f + fast_exp2(c1)), 2.f, -1.f);
            float h1u = vo * th1;          // every lane holds h1[own unit]
            butterfly8v(h1u, hx1);         // 3 swz + 4 dpp; pair 0 DPP-only

            // ---- layer 2: 4 pk_fma + pk_add + add on top of packed q ----
            v2f pA = pk_fma(hx1[0], wi2v[0], qA);
            v2f pB = pk_fma(hx1[1], wi2v[1], qB);
            pA = pk_fma(hx1[2], wi2v[2], pA);
            pB = pk_fma(hx1[3], wi2v[3], pB);
            v2f pC = pk_add(pA, pB);
            float acc2 = pC.x + pC.y;

            float u0 = fmaf(fast_rcp(1.f + fast_exp2(acc2)), actMul, actAdd);
            float ui = dpp<DPP_BC0>(u0);
            float uf = dpp<DPP_BC1>(u0);
            float ug = dpp<DPP_BC2>(u0);
            float uo = dpp<DPP_BC3>(u0);
            c2 = fmaf(uf, c2, ui * ug);
            float th2 = fmaf(fast_rcp(1.f + fast_exp2(c2)), 2.f, -1.f);
            float h2u = uo * th2;
            butterfly8v(h2u, hx2);
        }
    }

    // ---- BN (eval) + MLP head, one lane per batch element ----
    // At l5==0 (u==0): pairs hold units {0,2},{1,3},{4,6},{5,7}.
    if (l5 == 0) {
        float h2v[HID];
        h2v[0] = hx2[0].x; h2v[2] = hx2[0].y;
        h2v[1] = hx2[1].x; h2v[3] = hx2[1].y;
        h2v[4] = hx2[2].x; h2v[6] = hx2[2].y;
        h2v[5] = hx2[3].x; h2v[7] = hx2[3].y;
        float nd[HID];
#pragma unroll
        for (int j = 0; j < HID; ++j) {
            float inv = 1.f / sqrtf(bn_var[j] + BN_EPS);
            nd[j] = bn_gamma[j] * (h2v[j] - bn_mean[j]) * inv + bn_beta[j];
        }
        float acc = b2p[0];
#pragma unroll
        for (int m = 0; m < 4; ++m) {
            float s = b1p[m];
#pragma unroll
            for (int j = 0; j < HID; ++j) s = fmaf(nd[j], w1p[m * HID + j], s);
            s = fmaxf(s, 0.f);
            acc = fmaf(s, w2p[m], acc);
        }
        out[b] = acc;
    }
}

extern "C" void kernel_launch(void* const* d_in, const int* in_sizes, int n_in,
                              void* d_out, int out_size, void* d_ws, size_t ws_size,
                              hipStream_t stream) {
    const float* x        = (const float*)d_in[0];
    const float* Wih1     = (const float*)d_in[1];
    const float* Whh1     = (const float*)d_in[2];
    const float* bih1     = (const float*)d_in[3];
    const float* bhh1     = (const float*)d_in[4];
    const float* Wih2     = (const float*)d_in[5];
    const float* Whh2     = (const float*)d_in[6];
    const float* bih2     = (const float*)d_in[7];
    const float* bhh2     = (const float*)d_in[8];
    const float* bn_gamma = (const float*)d_in[9];
    const float* bn_beta  = (const float*)d_in[10];
    const float* bn_mean  = (const float*)d_in[11];
    const float* bn_var   = (const float*)d_in[12];
    const float* w1p      = (const float*)d_in[13];
    const float* b1p      = (const float*)d_in[14];
    const float* w2p      = (const float*)d_in[15];
    const float* b2p      = (const float*)d_in[16];
    float* out = (float*)d_out;

    const int B = in_sizes[0] / (T_SEQ * INPUT);   // 4096
    dim3 grid(B / 8), block(256);
    hipLaunchKernelGGL(lstm_forex_kernel, grid, block, 0, stream,
                       x, Wih1, Whh1, bih1, bhh1, Wih2, Whh2, bih2, bhh2,
                       bn_gamma, bn_beta, bn_mean, bn_var, w1p, b1p, w2p, b2p, out);
}